// Round 2
// baseline (295.512 us; speedup 1.0000x reference)
//
#include <hip/hip_runtime.h>

#define N_NODES_C 131072
#define N_EDGES_C 8388608
#define N_GRAPHS_C 64
#define NBLK 2048
#define BLK 256
#define NCOPY 4
#define CSTR 68   // padded copy stride: copies of bin g land in distinct banks

typedef int   vint4   __attribute__((ext_vector_type(4)));
typedef float vfloat4 __attribute__((ext_vector_type(4)));

__device__ __forceinline__ vint4 ldnt_i4(const vint4* p) {
    return __builtin_nontemporal_load(p);
}
__device__ __forceinline__ vfloat4 ldnt_f4(const vfloat4* p) {
    return __builtin_nontemporal_load(p);
}

__device__ __forceinline__ int lower_bound_dev(const int* a, int n, int v) {
    int lo = 0, hi = n;
    while (lo < hi) { int mid = (lo + hi) >> 1; if (a[mid] < v) lo = mid + 1; else hi = mid; }
    return lo;
}

// Pack {pos.x, pos.y, size.x (g in low 6 mantissa bits), size.y} per node.
// One 16B gather/endpoint, no separate batch[] gather.
__global__ void build_A_kernel(const float2* __restrict__ pos, const float2* __restrict__ sz,
                               const int* __restrict__ batch, float4* __restrict__ A) {
    int n = blockIdx.x * blockDim.x + threadIdx.x;
    if (n < N_NODES_C) {
        float2 p = pos[n]; float2 s = sz[n];
        unsigned u = __float_as_uint(s.x);
        u = (u & ~63u) | (unsigned)batch[n];
        A[n] = make_float4(p.x, p.y, __uint_as_float(u), s.y);
    }
}

// Edge pass 1: per-graph {sum r, sum r^2, sum normalized_overlap, edge count}.
__global__ __launch_bounds__(BLK, 4) void pass1_kernel(
    const int* __restrict__ idx0, const int* __restrict__ idx1,
    const float* __restrict__ attr, const float4* __restrict__ A,
    float* __restrict__ rsum_p, float* __restrict__ r2_p,
    float* __restrict__ ov_p, float* __restrict__ cnt_p) {
    __shared__ float sb_r[NCOPY * CSTR], sb_r2[NCOPY * CSTR];
    __shared__ float sb_ov[NCOPY * CSTR], sb_c[NCOPY * CSTR];
    int tid = threadIdx.x;
    for (int i = tid; i < NCOPY * CSTR; i += BLK) {
        sb_r[i] = 0.f; sb_r2[i] = 0.f; sb_ov[i] = 0.f; sb_c[i] = 0.f;
    }
    __syncthreads();
    const int copy_off = (tid & (NCOPY - 1)) * CSTR;
    const vint4*   v0 = (const vint4*)idx0;
    const vint4*   v1 = (const vint4*)idx1;
    const vfloat4* va = (const vfloat4*)attr;
    const int gid  = blockIdx.x * BLK + tid;
    const int GRID = NBLK * BLK;             // 524288; nvec = 2M = 4*GRID exactly
    #pragma unroll
    for (int half = 0; half < 2; ++half) {
        const int ia = gid + (2 * half + 0) * GRID;
        const int ib = gid + (2 * half + 1) * GRID;
        vint4 s4a = ldnt_i4(v0 + ia), s4b = ldnt_i4(v0 + ib);
        vint4 t4a = ldnt_i4(v1 + ia), t4b = ldnt_i4(v1 + ib);
        vfloat4 d4a = ldnt_f4(va + ia), d4b = ldnt_f4(va + ib);
        int   sidx[8] = {s4a.x, s4a.y, s4a.z, s4a.w, s4b.x, s4b.y, s4b.z, s4b.w};
        int   tidx[8] = {t4a.x, t4a.y, t4a.z, t4a.w, t4b.x, t4b.y, t4b.z, t4b.w};
        float dval[8] = {d4a.x, d4a.y, d4a.z, d4a.w, d4b.x, d4b.y, d4b.z, d4b.w};
        float4 As[8], At[8];
        #pragma unroll
        for (int k = 0; k < 8; ++k) { As[k] = A[sidx[k]]; At[k] = A[tidx[k]]; }
        #pragma unroll
        for (int k = 0; k < 8; ++k) {
            float4 as_ = As[k], at_ = At[k];
            int g = (int)(__float_as_uint(as_.z) & 63u);
            int b = copy_off + g;
            float dx = as_.x - at_.x, dy = as_.y - at_.y;
            float eu = sqrtf(dx * dx + dy * dy);
            float r = eu / dval[k];
            atomicAdd(&sb_r[b], r);
            atomicAdd(&sb_r2[b], r * r);
            float ox = fmaxf((as_.z + at_.z) * 0.5f - fabsf(dx), 0.f);
            float oy = fmaxf((as_.w + at_.w) * 0.5f - fabsf(dy), 0.f);
            float tot = as_.z + as_.w + at_.z + at_.w;
            atomicAdd(&sb_ov[b], (ox * oy) / tot);
            atomicAdd(&sb_c[b], 1.f);
        }
    }
    __syncthreads();
    if (tid < N_GRAPHS_C) {
        float r = 0.f, r2 = 0.f, ov = 0.f, c = 0.f;
        #pragma unroll
        for (int cpy = 0; cpy < NCOPY; ++cpy) {
            int b = cpy * CSTR + tid;
            r += sb_r[b]; r2 += sb_r2[b]; ov += sb_ov[b]; c += sb_c[b];
        }
        int o = tid * NBLK + blockIdx.x;
        rsum_p[o] = r; r2_p[o] = r2; ov_p[o] = ov; cnt_p[o] = c;
    }
}

__global__ void reduce1_kernel(const float* __restrict__ rsum_p, const float* __restrict__ r2_p,
                               const float* __restrict__ ov_p, const float* __restrict__ cnt_p,
                               const int* __restrict__ batch,
                               float* __restrict__ scale, float* __restrict__ gov,
                               float* __restrict__ gsize) {
    int g = blockIdx.x, tid = threadIdx.x;
    float a = 0.f, b = 0.f, c = 0.f, d = 0.f;
    for (int i = tid; i < NBLK; i += 256) {
        a += rsum_p[g * NBLK + i];
        b += r2_p[g * NBLK + i];
        c += ov_p[g * NBLK + i];
        d += cnt_p[g * NBLK + i];
    }
    __shared__ float sa[256], sb[256], sc[256], sd[256];
    sa[tid] = a; sb[tid] = b; sc[tid] = c; sd[tid] = d;
    __syncthreads();
    for (int s = 128; s > 0; s >>= 1) {
        if (tid < s) { sa[tid] += sa[tid+s]; sb[tid] += sb[tid+s]; sc[tid] += sc[tid+s]; sd[tid] += sd[tid+s]; }
        __syncthreads();
    }
    if (tid == 0) {
        scale[g] = sb[0] / sa[0];
        gov[g]   = sc[0] / fmaxf(sd[0], 1.f);
        int lo = lower_bound_dev(batch, N_NODES_C, g);
        int hi = lower_bound_dev(batch, N_NODES_C, g + 1);
        gsize[g] = (float)(hi - lo);
    }
}

// Pack {pos/scale, graph_id_bits, unused} per node for pass 2.
__global__ void build_B_kernel(const float2* __restrict__ pos, const int* __restrict__ batch,
                               const float* __restrict__ scale, float4* __restrict__ B) {
    int n = blockIdx.x * blockDim.x + threadIdx.x;
    if (n < N_NODES_C) {
        int g = batch[n];
        float s = scale[g];
        float2 p = pos[n];
        B[n] = make_float4(p.x / s, p.y / s, __int_as_float(g), 0.f);
    }
}

// Edge pass 2: per-graph stress sum with scaled positions.
__global__ __launch_bounds__(BLK, 4) void pass2_kernel(
    const int* __restrict__ idx0, const int* __restrict__ idx1,
    const float* __restrict__ attr, const float4* __restrict__ B,
    float* __restrict__ st_p) {
    __shared__ float sbn[NCOPY * CSTR];
    int tid = threadIdx.x;
    for (int i = tid; i < NCOPY * CSTR; i += BLK) sbn[i] = 0.f;
    __syncthreads();
    const int copy_off = (tid & (NCOPY - 1)) * CSTR;
    const vint4*   v0 = (const vint4*)idx0;
    const vint4*   v1 = (const vint4*)idx1;
    const vfloat4* va = (const vfloat4*)attr;
    const int gid  = blockIdx.x * BLK + tid;
    const int GRID = NBLK * BLK;
    #pragma unroll
    for (int half = 0; half < 2; ++half) {
        const int ia = gid + (2 * half + 0) * GRID;
        const int ib = gid + (2 * half + 1) * GRID;
        vint4 s4a = ldnt_i4(v0 + ia), s4b = ldnt_i4(v0 + ib);
        vint4 t4a = ldnt_i4(v1 + ia), t4b = ldnt_i4(v1 + ib);
        vfloat4 d4a = ldnt_f4(va + ia), d4b = ldnt_f4(va + ib);
        int   sidx[8] = {s4a.x, s4a.y, s4a.z, s4a.w, s4b.x, s4b.y, s4b.z, s4b.w};
        int   tidx[8] = {t4a.x, t4a.y, t4a.z, t4a.w, t4b.x, t4b.y, t4b.z, t4b.w};
        float dval[8] = {d4a.x, d4a.y, d4a.z, d4a.w, d4b.x, d4b.y, d4b.z, d4b.w};
        float4 Bs[8], Bt[8];
        #pragma unroll
        for (int k = 0; k < 8; ++k) { Bs[k] = B[sidx[k]]; Bt[k] = B[tidx[k]]; }
        #pragma unroll
        for (int k = 0; k < 8; ++k) {
            float4 bs = Bs[k], bt = Bt[k];
            int g = __float_as_int(bs.z);
            float dx = bs.x - bt.x, dy = bs.y - bt.y;
            float eu2 = sqrtf(dx * dx + dy * dy);
            float q = (eu2 - dval[k]) / dval[k];
            atomicAdd(&sbn[copy_off + g], q * q);
        }
    }
    __syncthreads();
    if (tid < N_GRAPHS_C) {
        float s = 0.f;
        #pragma unroll
        for (int cpy = 0; cpy < NCOPY; ++cpy) s += sbn[cpy * CSTR + tid];
        st_p[tid * NBLK + blockIdx.x] = s;
    }
}

__global__ void reduce2_kernel(const float* __restrict__ st_p, const float* __restrict__ gsize,
                               const float* __restrict__ gov, float* __restrict__ comb) {
    int g = blockIdx.x, tid = threadIdx.x;
    float a = 0.f;
    for (int i = tid; i < NBLK; i += 256) a += st_p[g * NBLK + i];
    __shared__ float sm[256];
    sm[tid] = a;
    __syncthreads();
    for (int s = 128; s > 0; s >>= 1) {
        if (tid < s) sm[tid] += sm[tid + s];
        __syncthreads();
    }
    if (tid == 0) {
        float n = gsize[g];
        comb[g] = sm[0] / (n * n) + gov[g];
    }
}

__global__ void final_kernel(const float* __restrict__ comb, float* __restrict__ out) {
    float v = comb[threadIdx.x];
    #pragma unroll
    for (int off = 32; off > 0; off >>= 1) v += __shfl_down(v, off);
    if (threadIdx.x == 0) out[0] = v * (1.0f / 64.0f);
}

extern "C" void kernel_launch(void* const* d_in, const int* in_sizes, int n_in,
                              void* d_out, int out_size, void* d_ws, size_t ws_size,
                              hipStream_t stream) {
    const float* node_pos   = (const float*)d_in[0];   // (131072, 2)
    const float* node_sizes = (const float*)d_in[1];   // (131072, 2)
    const float* attr       = (const float*)d_in[2];   // (8388608, 1)
    const int*   eidx       = (const int*)d_in[3];     // (2, 8388608)
    const int*   batch      = (const int*)d_in[4];     // (131072,) sorted
    float* out = (float*)d_out;
    float* ws  = (float*)d_ws;

    const int P = N_GRAPHS_C * NBLK;   // 131072
    float* rsum_p = ws;                // reused by st_p after reduce1 consumes it
    float* r2_p   = ws + P;
    float* ov_p   = ws + 2 * P;
    float* cnt_p  = ws + 3 * P;
    float* st_p   = rsum_p;            // alias: pass2 runs after reduce1
    float* scale  = ws + 4 * P;        // 64
    float* gov    = scale + 64;        // 64
    float* gsize  = gov + 64;          // 64
    float* comb   = gsize + 64;        // 64
    float4* A = (float4*)(ws + 4 * P + 256);
    float4* B = A + N_NODES_C;

    const int* idx0 = eidx;
    const int* idx1 = eidx + N_EDGES_C;

    build_A_kernel<<<N_NODES_C / 256, 256, 0, stream>>>((const float2*)node_pos,
                                                        (const float2*)node_sizes, batch, A);
    pass1_kernel<<<NBLK, BLK, 0, stream>>>(idx0, idx1, attr, A,
                                           rsum_p, r2_p, ov_p, cnt_p);
    reduce1_kernel<<<N_GRAPHS_C, 256, 0, stream>>>(rsum_p, r2_p, ov_p, cnt_p, batch,
                                                   scale, gov, gsize);
    build_B_kernel<<<N_NODES_C / 256, 256, 0, stream>>>((const float2*)node_pos, batch, scale, B);
    pass2_kernel<<<NBLK, BLK, 0, stream>>>(idx0, idx1, attr, B, st_p);
    reduce2_kernel<<<N_GRAPHS_C, 256, 0, stream>>>(st_p, gsize, gov, comb);
    final_kernel<<<1, 64, 0, stream>>>(comb, out);
}